// Round 9
// baseline (2426.388 us; speedup 1.0000x reference)
//
#include <hip/hip_runtime.h>

// Scatter-mean graph propagation, 8 rounds (4 fwd + 4 rev).
//
// Round-8 post-mortem: t_pass2 latency-bound: 128KB LDS -> 1 block/CU (16
// waves), and each of 31 phases paid an unprefetched packed2 load chain
// (~16.6K cy/phase for ~4 edges/thread). Round-9 t_pass3:
//   - acc = 2 dbs = 8192 nodes (32KB); xt = 4096-node src tile, dbuf 2x16KB
//     -> 64KB LDS -> 2 blocks/CU, 32 waves/CU (__launch_bounds__(1024,8)).
//   - cross-phase REGISTER PREFETCH: at phase start, issue next phase's
//     packed2 words (1-2 per thread, addrs from LDS-cached celloff) and the
//     x-tile for phase+2 (1 float4/thread); consume after the barrier.
//     Phase critical path becomes LDS ops + 1 barrier.
//   - b_repart now bins by src>>12 (245 bins, NSBMAX 256, 64KB stg).
// Pipeline: phase A dst-partition (proven) -> c_pass counts -> b_repart ->
// 4x (t_pass3 + combine2_k) per direction. Partials alias dead packed1.
//
// MID PATH (ws too small): phase A + c_pass + gather e_pass (round-5, 188us).
// FALLBACK: global-atomic version.

typedef unsigned uint32x4 __attribute__((ext_vector_type(4)));

#define TPB_E 1024
#define NPART 512
#define TPB_P 512
#define BATCHA 8192
#define CAPA 64
#define NDBMAX 256     // max dst buckets (N <= 2^20)
#define DSH 12         // dst bucket shift (4096 nodes)
#define DMASK 4095u
#define SSH 12         // src tile shift (4096 nodes) -- matches xt size
#define NSBMAX 256
#define BATCHB 4096
#define CAPB 64
#define SUPER 2        // dbs per t_pass3 block (acc = SUPER<<DSH floats)
#define NC 4           // src-range chunks per super
#define SUPSH 13       // log2(SUPER<<DSH)

// ---------------- phase A: partition by dst bucket ----------------

__global__ __launch_bounds__(TPB_P)
void p1_count(const int* __restrict__ dst, unsigned* __restrict__ blkcnt,
              int E, int chunk, int NB) {
    __shared__ unsigned h[NDBMAX];
    for (int i = threadIdx.x; i < NB; i += TPB_P) h[i] = 0u;
    __syncthreads();
    int beg = blockIdx.x * chunk;
    int end = min(beg + chunk, E);
    int len = end - beg; if (len < 0) len = 0;
    const uint32x4* d4 = (const uint32x4*)(dst + beg);   // beg multiple of 16
    int n4 = len >> 2;
    for (int i = threadIdx.x; i < n4; i += TPB_P) {
        uint32x4 d = __builtin_nontemporal_load(&d4[i]);
        atomicAdd(&h[d.x >> DSH], 1u);
        atomicAdd(&h[d.y >> DSH], 1u);
        atomicAdd(&h[d.z >> DSH], 1u);
        atomicAdd(&h[d.w >> DSH], 1u);
    }
    __syncthreads();
    unsigned* o = blkcnt + (size_t)blockIdx.x * NB;
    for (int i = threadIdx.x; i < NB; i += TPB_P) o[i] = h[i];
}

__global__ __launch_bounds__(TPB_P)
void s1_totals(const unsigned* __restrict__ blkcnt, unsigned* __restrict__ totals,
               int NB, int nblk) {
    __shared__ unsigned red[TPB_P];
    int b = blockIdx.x;
    unsigned s = 0;
    for (int k = threadIdx.x; k < nblk; k += TPB_P) s += blkcnt[(size_t)k * NB + b];
    red[threadIdx.x] = s;
    __syncthreads();
    for (int off = TPB_P / 2; off > 0; off >>= 1) {
        if (threadIdx.x < off) red[threadIdx.x] += red[threadIdx.x + off];
        __syncthreads();
    }
    if (threadIdx.x == 0) totals[b] = red[0];
}

__global__ __launch_bounds__(TPB_P)
void s2_scan(const unsigned* __restrict__ totals, unsigned* __restrict__ base, int NB) {
    __shared__ unsigned t[TPB_P];
    int tid = threadIdx.x;
    unsigned v = (tid < NB) ? totals[tid] : 0u;
    t[tid] = v;
    __syncthreads();
    for (int off = 1; off < TPB_P; off <<= 1) {
        unsigned w = (tid >= off) ? t[tid - off] : 0u;
        __syncthreads();
        t[tid] += w;
        __syncthreads();
    }
    if (tid < NB) base[tid] = t[tid] - v;
    if (tid == NB - 1) base[NB] = t[tid];
}

__global__ __launch_bounds__(TPB_P)
void s3_start(const unsigned* __restrict__ blkcnt, const unsigned* __restrict__ base,
              unsigned* __restrict__ start, int NB, int nblk) {
    __shared__ unsigned t[TPB_P];
    int b = blockIdx.x;
    int tid = threadIdx.x;
    unsigned v = (tid < nblk) ? blkcnt[(size_t)tid * NB + b] : 0u;
    t[tid] = v;
    __syncthreads();
    for (int off = 1; off < TPB_P; off <<= 1) {
        unsigned w = (tid >= off) ? t[tid - off] : 0u;
        __syncthreads();
        t[tid] += w;
        __syncthreads();
    }
    if (tid < nblk) start[(size_t)tid * NB + b] = base[b] + t[tid] - v;
}

__global__ __launch_bounds__(TPB_P)
void p2_scatter(const int* __restrict__ src, const int* __restrict__ dst,
                const unsigned* __restrict__ start, unsigned* __restrict__ packed,
                int E, int chunk, int NB) {
    __shared__ unsigned stg[NDBMAX * CAPA];   // 64 KB staging
    __shared__ unsigned h[NDBMAX];
    __shared__ unsigned gcur[NDBMAX];
    int tid = threadIdx.x;
    int bid = blockIdx.x;
    for (int i = tid; i < NB; i += TPB_P) gcur[i] = start[(size_t)bid * NB + i];
    int beg = bid * chunk;
    int end = min(beg + chunk, E);
    int wid = tid >> 6, lane = tid & 63;
    for (int bb = beg; bb < end; bb += BATCHA) {
        int bend = min(bb + BATCHA, end);
        int n4 = (bend - bb) >> 2;          // batch multiple of 16
        for (int i = tid; i < NB; i += TPB_P) h[i] = 0u;
        __syncthreads();
        const uint32x4* s4 = (const uint32x4*)(src + bb);
        const uint32x4* d4 = (const uint32x4*)(dst + bb);
        for (int i = tid; i < n4; i += TPB_P) {
            uint32x4 s = __builtin_nontemporal_load(&s4[i]);
            uint32x4 d = __builtin_nontemporal_load(&d4[i]);
            unsigned sv[4] = {s.x, s.y, s.z, s.w};
            unsigned dv[4] = {d.x, d.y, d.z, d.w};
            #pragma unroll
            for (int k = 0; k < 4; ++k) {
                unsigned b = dv[k] >> DSH;
                unsigned val = (sv[k] << DSH) | (dv[k] & DMASK);
                unsigned pos = atomicAdd(&h[b], 1u);
                if (pos < CAPA) stg[(b << 6) + ((pos + b) & 63u)] = val;  // bank-rotated
                else packed[gcur[b] + pos] = val;   // rare overflow
            }
        }
        __syncthreads();
        for (int b = wid; b < NB; b += TPB_P / 64) {
            unsigned cnt = h[b];
            unsigned n = cnt < CAPA ? cnt : CAPA;
            unsigned g0 = gcur[b];
            for (unsigned i = lane; i < n; i += 64)
                packed[g0 + i] = stg[(b << 6) + ((i + b) & 63u)];
            if (lane == 0) gcur[b] = g0 + cnt;
        }
        __syncthreads();
    }
}

// ---------------- counts (once per direction) ----------------

__global__ __launch_bounds__(TPB_E)
void c_pass(const unsigned* __restrict__ packed1, const unsigned* __restrict__ base,
            float* __restrict__ cnt, int N) {
    __shared__ unsigned c[1 << DSH];   // 16 KB
    int db = blockIdx.x, tid = threadIdx.x;
    for (int i = tid; i < (1 << DSH); i += TPB_E) c[i] = 0u;
    __syncthreads();
    int beg = (int)base[db], end = (int)base[db + 1];
    for (int e = beg + tid; e < end; e += TPB_E)
        atomicAdd(&c[packed1[e] & DMASK], 1u);
    __syncthreads();
    int nbase = db << DSH;
    int nmax = min(N - nbase, 1 << DSH);
    for (int i = tid; i < nmax; i += TPB_E) cnt[nbase + i] = (float)c[i];
}

// ---------------- phase B: per-db re-sort by src tile (4096-node tiles) ----------------

__global__ __launch_bounds__(TPB_E)
void b_repart(const unsigned* __restrict__ packed1, const unsigned* __restrict__ base,
              unsigned* __restrict__ packed2, unsigned* __restrict__ celloff,
              int NSB) {
    __shared__ unsigned h[NSBMAX];
    __shared__ unsigned gcur[NSBMAX];
    __shared__ unsigned stg[NSBMAX * CAPB];   // 64 KB
    int db = blockIdx.x;
    int tid = threadIdx.x;
    int segbeg = (int)base[db], segend = (int)base[db + 1];
    for (int i = tid; i < NSB; i += TPB_E) h[i] = 0u;
    __syncthreads();
    for (int e = segbeg + tid; e < segend; e += TPB_E)
        atomicAdd(&h[packed1[e] >> (DSH + SSH)], 1u);
    __syncthreads();
    if (tid == 0) {   // tiny serial scan (<=256 elements)
        unsigned run = (unsigned)segbeg;
        for (int i = 0; i < NSB; ++i) {
            unsigned c = h[i];
            gcur[i] = run;
            celloff[(size_t)db * (NSB + 1) + i] = run;
            run += c;
        }
        celloff[(size_t)db * (NSB + 1) + NSB] = run;   // == segend
    }
    __syncthreads();
    int wid = tid >> 6, lane = tid & 63;
    for (int bb = segbeg; bb < segend; bb += BATCHB) {
        int bend = min(bb + BATCHB, segend);
        for (int i = tid; i < NSB; i += TPB_E) h[i] = 0u;
        __syncthreads();
        for (int e = bb + tid; e < bend; e += TPB_E) {
            unsigned p = packed1[e];
            unsigned sb = p >> (DSH + SSH);
            unsigned v = ((p >> DSH) & ((1u << SSH) - 1u)) << DSH | (p & DMASK);
            unsigned pos = atomicAdd(&h[sb], 1u);
            if (pos < CAPB) stg[(sb << 6) + ((pos + sb) & 63u)] = v;
            else packed2[gcur[sb] + pos] = v;
        }
        __syncthreads();
        for (int b = wid; b < NSB; b += TPB_E / 64) {
            unsigned cnt = h[b];
            unsigned n = cnt < CAPB ? cnt : CAPB;
            unsigned g0 = gcur[b];
            for (unsigned i = lane; i < n; i += 64)
                packed2[g0 + i] = stg[(b << 6) + ((i + b) & 63u)];
            if (lane == 0) gcur[b] = g0 + cnt;
        }
        __syncthreads();
    }
}

// ---------------- t_pass3: fully-prefetched LDS edge pass ----------------
// block = (super s: 2 dbs, chunk c). acc 32KB + xt 2x16KB = 64KB -> 2 blk/CU.

__global__ __launch_bounds__(TPB_E, 8)
void t_pass3(const float* __restrict__ x, const unsigned* __restrict__ packed2,
             const unsigned* __restrict__ celloff, float* __restrict__ partial,
             int N, int NDB, int NSB) {
    __shared__ float acc[SUPER << DSH];        // 8192 floats = 32 KB
    __shared__ float xt[2][1 << SSH];          // 2 x 4096 floats = 32 KB
    __shared__ unsigned co2[2 * (NSBMAX + 1)]; // cached celloff rows
    const int tid = threadIdx.x;
    const int s = blockIdx.x;
    const int c = blockIdx.y;
    const int tiles_per = (NSB + NC - 1) / NC;
    const int sb0 = c * tiles_per;
    const int sb1 = min(sb0 + tiles_per, NSB);

    for (int i = tid; i < (SUPER << DSH); i += TPB_E) acc[i] = 0.0f;
    // cache celloff rows for this block's 2 dbs (0 if db out of range)
    for (int i = tid; i < 2 * (NSB + 1); i += TPB_E) {
        int jrr = i / (NSB + 1), ii = i - jrr * (NSB + 1);
        int dbr = s * SUPER + jrr;
        co2[jrr * (NSBMAX + 1) + ii] =
            (dbr < NDB) ? celloff[(size_t)dbr * (NSB + 1) + ii] : 0u;
    }
    __syncthreads();

    const int wid = tid >> 6, lane = tid & 63;
    const int jr = wid & 1;                        // which db of the super
    const int gid = ((wid >> 1) << 6) | lane;      // 0..511 within run
    const unsigned* myco = &co2[jr * (NSBMAX + 1)];
    const unsigned jb = (unsigned)jr << DSH;

    // guarded x-tile load (1 float4/thread covers 4096 floats)
    auto load_tile = [&](int sb) -> float4 {
        int idx = (sb << SSH) + (tid << 2);
        if (idx + 3 < N) return *(const float4*)(x + idx);
        float4 r; r.x = r.y = r.z = r.w = 0.0f;
        if (idx < N)     r.x = x[idx];
        if (idx + 1 < N) r.y = x[idx + 1];
        if (idx + 2 < N) r.z = x[idx + 2];
        if (idx + 3 < N) r.w = x[idx + 3];
        return r;
    };

    if (sb0 < sb1) {
        // prologue: stage xt[0] = tile sb0; RX = tile sb0+1; prefetch edges sb0
        float4 t0 = load_tile(sb0);
        ((float4*)xt[0])[tid] = t0;
        float4 RX;
        if (sb0 + 1 < sb1) RX = load_tile(sb0 + 1);
        int cb = (int)myco[sb0];
        int cl = (int)myco[sb0 + 1] - cb;
        unsigned v0 = 0, v1 = 0;
        if (gid < cl)       v0 = packed2[cb + gid];
        if (gid + 512 < cl) v1 = packed2[cb + gid + 512];
        __syncthreads();

        int cur = 0;
        for (int sb = sb0; sb < sb1; ++sb) {
            // issue NEXT phase's loads first (consumed after the barrier)
            int nb = 0, nl = 0;
            unsigned n0 = 0, n1 = 0;
            if (sb + 1 < sb1) {
                nb = (int)myco[sb + 1];
                nl = (int)myco[sb + 2] - nb;
                if (gid < nl)       n0 = packed2[nb + gid];
                if (gid + 512 < nl) n1 = packed2[nb + gid + 512];
                ((float4*)xt[cur ^ 1])[tid] = RX;     // write tile sb+1
                if (sb + 2 < sb1) RX = load_tile(sb + 2);
            }
            // process current phase from prefetched regs
            const float* xb = xt[cur];
            if (gid < cl)
                atomicAdd(&acc[jb + (v0 & DMASK)], xb[v0 >> DSH]);
            if (gid + 512 < cl)
                atomicAdd(&acc[jb + (v1 & DMASK)], xb[v1 >> DSH]);
            for (int e = cb + gid + 1024; e < cb + cl; e += 512) {  // ~never
                unsigned p = packed2[e];
                atomicAdd(&acc[jb + (p & DMASK)], xb[p >> DSH]);
            }
            __syncthreads();
            cb = nb; cl = nl; v0 = n0; v1 = n1; cur ^= 1;
        }
    }
    // dump partial accumulator (coalesced)
    float* po = partial + (((size_t)s * NC + c) << SUPSH);
    for (int i = tid; i < (SUPER << DSH); i += TPB_E) po[i] = acc[i];
}

// combine NC partials per super (span 8192 nodes), divide by cnt
__global__ void combine2_k(const float* __restrict__ partial, const float* __restrict__ cnt,
                           float* __restrict__ outslice, int N) {
    int tot4 = N >> 2;
    int stride = gridDim.x * blockDim.x;
    for (int n4 = blockIdx.x * blockDim.x + threadIdx.x; n4 < tot4; n4 += stride) {
        int n = n4 << 2;
        int s = n >> SUPSH;
        int i = n & ((SUPER << DSH) - 1);
        const float* pb = partial + (((size_t)s * NC) << SUPSH) + i;
        float4 sum = *(const float4*)pb;
        #pragma unroll
        for (int cc = 1; cc < NC; ++cc) {
            float4 v = *(const float4*)(pb + ((size_t)cc << SUPSH));
            sum.x += v.x; sum.y += v.y; sum.z += v.z; sum.w += v.w;
        }
        float4 cv = *(const float4*)(cnt + n);
        float4 o;
        o.x = sum.x / fmaxf(cv.x, 1.0f);
        o.y = sum.y / fmaxf(cv.y, 1.0f);
        o.z = sum.z / fmaxf(cv.z, 1.0f);
        o.w = sum.w / fmaxf(cv.w, 1.0f);
        *(float4*)(outslice + n) = o;
    }
    if (blockIdx.x == 0) {   // scalar tail
        for (int n = (tot4 << 2) + threadIdx.x; n < N; n += blockDim.x) {
            int s = n >> SUPSH;
            int i = n & ((SUPER << DSH) - 1);
            float sum = 0.0f;
            for (int cc = 0; cc < NC; ++cc)
                sum += partial[(((size_t)s * NC + cc) << SUPSH) + i];
            outslice[n] = sum / fmaxf(cnt[n], 1.0f);
        }
    }
}

// ---------------- mid path: gather-style edge pass (round-5 proven) ----------------

__global__ __launch_bounds__(TPB_E)
void e_pass12(const float* __restrict__ x, const unsigned* __restrict__ packed,
              const unsigned* __restrict__ boff, const float* __restrict__ cnt,
              float* __restrict__ outslice, int N) {
    __shared__ float acc[1 << DSH];
    int tid = threadIdx.x;
    for (int i = tid; i < (1 << DSH); i += TPB_E) acc[i] = 0.0f;
    __syncthreads();
    int b = blockIdx.x;
    int beg = (int)boff[b], end = (int)boff[b + 1];
    int a0 = min((beg + 3) & ~3, end);
    for (int e = beg + tid; e < a0; e += TPB_E) {
        unsigned p = packed[e];
        atomicAdd(&acc[p & DMASK], x[p >> DSH]);
    }
    int i0 = a0 >> 2, i1 = i0 + ((end - a0) >> 2);
    const uint32x4* p4 = (const uint32x4*)packed;
    for (int i = i0 + tid; i < i1; i += TPB_E) {
        uint32x4 p = p4[i];
        atomicAdd(&acc[p.x & DMASK], x[p.x >> DSH]);
        atomicAdd(&acc[p.y & DMASK], x[p.y >> DSH]);
        atomicAdd(&acc[p.z & DMASK], x[p.z >> DSH]);
        atomicAdd(&acc[p.w & DMASK], x[p.w >> DSH]);
    }
    for (int e = a0 + ((end - a0) & ~3) + tid; e < end; e += TPB_E) {
        unsigned p = packed[e];
        atomicAdd(&acc[p & DMASK], x[p >> DSH]);
    }
    __syncthreads();
    int nbase = b << DSH;
    int nmax = min(N - nbase, 1 << DSH);
    for (int i = tid; i < nmax; i += TPB_E)
        outslice[nbase + i] = acc[i] / fmaxf(cnt[nbase + i], 1.0f);
}

// ---------------- fallback (global atomics) ----------------

#define TPB 256
#define MAX_BLOCKS 2048

__global__ void round_first(const float* __restrict__ x, const int* __restrict__ src,
                            const int* __restrict__ dst, float* __restrict__ agg,
                            float* __restrict__ cnt, int nE) {
    int i = blockIdx.x * blockDim.x + threadIdx.x;
    int stride = gridDim.x * blockDim.x;
    for (; i < nE; i += stride) {
        atomicAdd(&agg[dst[i]], x[src[i]]);
        atomicAdd(&cnt[dst[i]], 1.0f);
    }
}

__global__ void round_next(const float* __restrict__ x, const int* __restrict__ src,
                           const int* __restrict__ dst, float* __restrict__ agg, int nE) {
    int i = blockIdx.x * blockDim.x + threadIdx.x;
    int stride = gridDim.x * blockDim.x;
    for (; i < nE; i += stride) atomicAdd(&agg[dst[i]], x[src[i]]);
}

__global__ void normalize_k(float* __restrict__ out, const float* __restrict__ cnt, int n) {
    int i = blockIdx.x * blockDim.x + threadIdx.x;
    int stride = gridDim.x * blockDim.x;
    for (; i < n; i += stride) out[i] /= fmaxf(cnt[i], 1.0f);
}

// ---------------- launch ----------------

extern "C" void kernel_launch(void* const* d_in, const int* in_sizes, int n_in,
                              void* d_out, int out_size, void* d_ws, size_t ws_size,
                              hipStream_t stream) {
    const float* topic = (const float*)d_in[0];
    const int* ei  = (const int*)d_in[1];
    const int* rei = (const int*)d_in[2];
    const int N = in_sizes[0];
    const int E = in_sizes[1] / 2;

    float* out = (float*)d_out;   // 8 slices of N floats

    const int NDB = (N + (int)DMASK) >> DSH;
    const int NSB = (N + ((1 << SSH) - 1)) >> SSH;
    const int NSUP = (NDB + SUPER - 1) / SUPER;
    const int chunk = ((E + NPART * 16 - 1) / (NPART * 16)) * 16;

    size_t off = 0;
    auto alloc = [&](size_t bytes) { size_t o = off; off += (bytes + 255) & ~(size_t)255; return o; };
    size_t o_packed1 = alloc((size_t)E * 4);
    size_t o_cnt     = alloc((size_t)N * 4);
    size_t o_blkcnt  = alloc((size_t)NPART * NDB * 4);
    size_t o_start   = alloc((size_t)NPART * NDB * 4);
    size_t o_base    = alloc((size_t)(NDBMAX + 1) * 4);
    size_t need_mid  = off;
    size_t o_packed2 = alloc((size_t)E * 4);
    size_t o_celloff = alloc((size_t)NDB * (NSB + 1) * 4);
    size_t need_2d   = off;

    // partial accumulators reuse the packed1 region (dead after b_repart)
    size_t partial_elems = (size_t)NSUP * NC * (SUPER << DSH);

    bool shapes_ok = (NDB >= 2) && (NDB <= NDBMAX) && (NSB >= 1) && (NSB <= NSBMAX) &&
                     (N <= (1 << 20)) && (E % 16 == 0) && (E > 0);
    bool full = shapes_ok && (need_2d <= ws_size) && (partial_elems <= (size_t)E);
    bool mid  = shapes_ok && (need_mid <= ws_size);

    if (full || mid) {
        char* ws = (char*)d_ws;
        unsigned* packed1 = (unsigned*)(ws + o_packed1);
        float*    cnt     = (float*)   (ws + o_cnt);
        unsigned* blkcnt  = (unsigned*)(ws + o_blkcnt);
        unsigned* start   = (unsigned*)(ws + o_start);
        unsigned* base    = (unsigned*)(ws + o_base);
        unsigned* packed2 = full ? (unsigned*)(ws + o_packed2) : nullptr;
        unsigned* celloff = full ? (unsigned*)(ws + o_celloff) : nullptr;
        float*    partial = (float*)(ws + o_packed1);   // alias, safe ordering

        for (int dir = 0; dir < 2; ++dir) {
            const int* src = (dir == 0) ? ei : rei;
            const int* dst = src + E;
            float* oslab = out + (size_t)dir * 4 * N;

            // phase A ('start' head doubles as totals scratch; s3 overwrites it)
            p1_count<<<NPART, TPB_P, 0, stream>>>(dst, blkcnt, E, chunk, NDB);
            s1_totals<<<NDB, TPB_P, 0, stream>>>(blkcnt, start, NDB, NPART);
            s2_scan<<<1, TPB_P, 0, stream>>>(start, base, NDB);
            s3_start<<<NDB, TPB_P, 0, stream>>>(blkcnt, base, start, NDB, NPART);
            p2_scatter<<<NPART, TPB_P, 0, stream>>>(src, dst, start, packed1, E, chunk, NDB);

            c_pass<<<NDB, TPB_E, 0, stream>>>(packed1, base, cnt, N);

            if (full) {
                b_repart<<<NDB, TPB_E, 0, stream>>>(packed1, base, packed2, celloff, NSB);
                // packed1 is now dead -> its space holds 'partial'
                dim3 tg(NSUP, NC);
                const float* xin = topic;
                for (int r = 0; r < 4; ++r) {
                    t_pass3<<<tg, TPB_E, 0, stream>>>(xin, packed2, celloff, partial,
                                                      N, NDB, NSB);
                    combine2_k<<<1024, 256, 0, stream>>>(partial, cnt,
                                                         oslab + (size_t)r * N, N);
                    xin = oslab + (size_t)r * N;
                }
            } else {
                e_pass12<<<NDB, TPB_E, 0, stream>>>(topic, packed1, base, cnt, oslab, N);
                for (int r = 1; r < 4; ++r)
                    e_pass12<<<NDB, TPB_E, 0, stream>>>(oslab + (size_t)(r - 1) * N, packed1,
                                                        base, cnt, oslab + (size_t)r * N, N);
            }
        }
        return;
    }

    // -------- fallback: global-atomic version --------
    const int* src = ei;
    const int* dst = ei + E;
    const int* rsrc = rei;
    const int* rdst = rei + E;

    float* cnt_f = (float*)d_ws;
    float* cnt_r = cnt_f + N;

    (void)hipMemsetAsync(d_out, 0, (size_t)out_size * sizeof(float), stream);
    (void)hipMemsetAsync(d_ws, 0, (size_t)2 * N * sizeof(float), stream);

    int eb = (E + TPB - 1) / TPB; if (eb > MAX_BLOCKS) eb = MAX_BLOCKS;
    int nb = (N + TPB - 1) / TPB; if (nb > MAX_BLOCKS) nb = MAX_BLOCKS;

    round_first<<<eb, TPB, 0, stream>>>(topic, src, dst, out, cnt_f, E);
    normalize_k<<<nb, TPB, 0, stream>>>(out, cnt_f, N);
    for (int r = 1; r < 4; ++r) {
        round_next<<<eb, TPB, 0, stream>>>(out + (size_t)(r - 1) * N, src, dst,
                                           out + (size_t)r * N, E);
        normalize_k<<<nb, TPB, 0, stream>>>(out + (size_t)r * N, cnt_f, N);
    }
    round_first<<<eb, TPB, 0, stream>>>(topic, rsrc, rdst, out + (size_t)4 * N, cnt_r, E);
    normalize_k<<<nb, TPB, 0, stream>>>(out + (size_t)4 * N, cnt_r, N);
    for (int r = 5; r < 8; ++r) {
        round_next<<<eb, TPB, 0, stream>>>(out + (size_t)(r - 1) * N, rsrc, rdst,
                                           out + (size_t)r * N, E);
        normalize_k<<<nb, TPB, 0, stream>>>(out + (size_t)r * N, cnt_r, N);
    }
}

// Round 10
// 1742.620 us; speedup vs baseline: 1.3924x; 1.3924x over previous
//
#include <hip/hip_runtime.h>

// Scatter-mean graph propagation, 8 rounds (4 fwd + 4 rev).
//
// ROUND-10: restore the round-5 proven pipeline (best measured: 1722us,
// e_pass 188us) and touch ONLY the e_pass inner loop:
//   - 8-wide unroll, all 8 x[src] gathers issued before the 8 LDS atomics
//     (deeper MLP on the gather latency chain; TA was ~55% busy at r5).
//   - nontemporal loads on the packed edge stream (keep the 4MB x array
//     resident in per-XCD L2; the stream is read once per pass).
//   - counts stored as reciprocals (multiply instead of divide per node).
// Rounds 6-9 lesson: 2D tiling with barrier-phased LDS staging loses to the
// simple gather (CDNA __syncthreads drains vmcnt(0) -> per-phase prefetch is
// impossible at HIP level; 3 structures all landed 210-290us/pass vs 188).
//
// Structure per direction (round-5, proven):
//   partition edges into NB=ceil(N/2048) buckets by dst>>11 (histogram ->
//   scan -> LDS-staged scatter, coalesced writes), packing each edge as
//   (src<<11)|(dst&2047) in one uint32 (needs N <= 2^20).
//   each round: one block (1024 thr) per bucket, LDS fp32 accumulation into
//   acc[2048], fused normalize, direct write to the round's output slice.
//
// FALLBACK (ws too small / shapes unexpected): proven global-atomic version.

typedef unsigned uint32x4 __attribute__((ext_vector_type(4)));

#define TPB_E 1024
#define NPART 512
#define TPB_P 512
#define BATCH 8192
#define CAP 32
#define NBMAX 512      // max buckets (N <= 2^20 -> NB <= 512)
#define BSH 11         // bucket shift
#define BSZ 2048       // nodes per bucket
#define BMASK 2047u

// ---------------- fast path ----------------

__global__ __launch_bounds__(TPB_P)
void p1_count(const int* __restrict__ dst, unsigned* __restrict__ blkcnt,
              int E, int chunk, int NB) {
    __shared__ unsigned h[NBMAX];
    for (int i = threadIdx.x; i < NB; i += TPB_P) h[i] = 0u;
    __syncthreads();
    int beg = blockIdx.x * chunk;
    int end = min(beg + chunk, E);
    int len = end - beg; if (len < 0) len = 0;
    const uint32x4* d4 = (const uint32x4*)(dst + beg);   // beg multiple of 16 -> aligned
    int n4 = len >> 2;
    for (int i = threadIdx.x; i < n4; i += TPB_P) {
        uint32x4 d = __builtin_nontemporal_load(&d4[i]);
        atomicAdd(&h[d.x >> BSH], 1u);
        atomicAdd(&h[d.y >> BSH], 1u);
        atomicAdd(&h[d.z >> BSH], 1u);
        atomicAdd(&h[d.w >> BSH], 1u);
    }
    __syncthreads();
    unsigned* o = blkcnt + (size_t)blockIdx.x * NB;
    for (int i = threadIdx.x; i < NB; i += TPB_P) o[i] = h[i];
}

// block per bucket: total over partition blocks
__global__ __launch_bounds__(TPB_P)
void s1_totals(const unsigned* __restrict__ blkcnt, unsigned* __restrict__ totals,
               int NB, int nblk) {
    __shared__ unsigned red[TPB_P];
    int b = blockIdx.x;
    unsigned s = 0;
    for (int k = threadIdx.x; k < nblk; k += TPB_P) s += blkcnt[(size_t)k * NB + b];
    red[threadIdx.x] = s;
    __syncthreads();
    for (int off = TPB_P / 2; off > 0; off >>= 1) {
        if (threadIdx.x < off) red[threadIdx.x] += red[threadIdx.x + off];
        __syncthreads();
    }
    if (threadIdx.x == 0) totals[b] = red[0];
}

// one block: exclusive scan of <=512 bucket totals; base[NB] = E
__global__ __launch_bounds__(TPB_P)
void s2_scan(const unsigned* __restrict__ totals, unsigned* __restrict__ base, int NB) {
    __shared__ unsigned t[TPB_P];
    int tid = threadIdx.x;
    unsigned v = (tid < NB) ? totals[tid] : 0u;
    t[tid] = v;
    __syncthreads();
    for (int off = 1; off < TPB_P; off <<= 1) {
        unsigned w = (tid >= off) ? t[tid - off] : 0u;
        __syncthreads();
        t[tid] += w;
        __syncthreads();
    }
    if (tid < NB) base[tid] = t[tid] - v;
    if (tid == NB - 1) base[NB] = t[tid];
}

// block per bucket: exclusive scan over partition blocks -> start positions
__global__ __launch_bounds__(TPB_P)
void s3_start(const unsigned* __restrict__ blkcnt, const unsigned* __restrict__ base,
              unsigned* __restrict__ start, int NB, int nblk) {
    __shared__ unsigned t[TPB_P];
    int b = blockIdx.x;
    int tid = threadIdx.x;
    unsigned v = (tid < nblk) ? blkcnt[(size_t)tid * NB + b] : 0u;
    t[tid] = v;
    __syncthreads();
    for (int off = 1; off < TPB_P; off <<= 1) {
        unsigned w = (tid >= off) ? t[tid - off] : 0u;
        __syncthreads();
        t[tid] += w;
        __syncthreads();
    }
    if (tid < nblk) start[(size_t)tid * NB + b] = base[b] + t[tid] - v;
}

// LDS-staged scatter with wave-cooperative coalesced flush
__global__ __launch_bounds__(TPB_P)
void p2_scatter(const int* __restrict__ src, const int* __restrict__ dst,
                const unsigned* __restrict__ start, unsigned* __restrict__ packed,
                int E, int chunk, int NB) {
    __shared__ unsigned stg[NBMAX * CAP];   // 64 KB staging
    __shared__ unsigned h[NBMAX];           // per-batch bucket counts
    __shared__ unsigned gcur[NBMAX];        // block's running global cursor
    int tid = threadIdx.x;
    int bid = blockIdx.x;
    for (int i = tid; i < NB; i += TPB_P) gcur[i] = start[(size_t)bid * NB + i];
    int beg = bid * chunk;
    int end = min(beg + chunk, E);
    int wid = tid >> 6, lane = tid & 63;
    for (int bb = beg; bb < end; bb += BATCH) {
        int bend = min(bb + BATCH, end);
        int n4 = (bend - bb) >> 2;          // batch size multiple of 16
        for (int i = tid; i < NB; i += TPB_P) h[i] = 0u;
        __syncthreads();
        const uint32x4* s4 = (const uint32x4*)(src + bb);
        const uint32x4* d4 = (const uint32x4*)(dst + bb);
        for (int i = tid; i < n4; i += TPB_P) {
            uint32x4 s = __builtin_nontemporal_load(&s4[i]);
            uint32x4 d = __builtin_nontemporal_load(&d4[i]);
            unsigned sv[4] = {s.x, s.y, s.z, s.w};
            unsigned dv[4] = {d.x, d.y, d.z, d.w};
            #pragma unroll
            for (int k = 0; k < 4; ++k) {
                unsigned b = dv[k] >> BSH;
                unsigned val = (sv[k] << BSH) | (dv[k] & BMASK);
                unsigned pos = atomicAdd(&h[b], 1u);
                if (pos < CAP) stg[(b << 5) + ((pos + b) & 31u)] = val;  // bank-rotated
                else packed[gcur[b] + pos] = val;   // rare overflow (Poisson tail)
            }
        }
        __syncthreads();
        // flush: wave w owns buckets w, w+NW, ... -> line-contiguous bursts
        for (int b = wid; b < NB; b += TPB_P / 64) {
            unsigned cnt = h[b];
            unsigned n = cnt < CAP ? cnt : CAP;
            unsigned g0 = gcur[b];
            for (unsigned i = lane; i < n; i += 64)
                packed[g0 + i] = stg[(b << 5) + ((i + b) & 31u)];
            if (lane == 0) gcur[b] = g0 + cnt;
        }
        __syncthreads();
    }
}

// one block per bucket; LDS accumulate; fused normalize; FIRST also builds
// reciprocal counts (rcnt[node] = 1/max(deg,1)); later passes multiply.
template <bool FIRST>
__global__ __launch_bounds__(TPB_E)
void e_pass(const float* __restrict__ x, const unsigned* __restrict__ packed,
            const unsigned* __restrict__ boff, float* __restrict__ rcnt,
            float* __restrict__ outslice, int N) {
    __shared__ float acc[BSZ];
    __shared__ unsigned c[FIRST ? BSZ : 1];
    int tid = threadIdx.x;
    for (int i = tid; i < BSZ; i += TPB_E) {
        acc[i] = 0.0f;
        if (FIRST) c[i] = 0u;
    }
    __syncthreads();
    int b = blockIdx.x;
    int beg = (int)boff[b], end = (int)boff[b + 1];
    int a0 = min((beg + 3) & ~3, end);
    for (int e = beg + tid; e < a0; e += TPB_E) {       // unaligned head
        unsigned p = packed[e];
        atomicAdd(&acc[p & BMASK], x[p >> BSH]);
        if (FIRST) atomicAdd(&c[p & BMASK], 1u);
    }
    int i0 = a0 >> 2, i1 = i0 + ((end - a0) >> 2);
    const uint32x4* p4 = (const uint32x4*)packed;
    // 8-wide body: two nt vector loads, 8 gathers in flight, then 8 atomics
    int i = i0 + tid;
    for (; i + TPB_E < i1; i += 2 * TPB_E) {
        uint32x4 a = __builtin_nontemporal_load(&p4[i]);
        uint32x4 bq = __builtin_nontemporal_load(&p4[i + TPB_E]);
        float xa0 = x[a.x >> BSH];
        float xa1 = x[a.y >> BSH];
        float xa2 = x[a.z >> BSH];
        float xa3 = x[a.w >> BSH];
        float xb0 = x[bq.x >> BSH];
        float xb1 = x[bq.y >> BSH];
        float xb2 = x[bq.z >> BSH];
        float xb3 = x[bq.w >> BSH];
        atomicAdd(&acc[a.x & BMASK], xa0);
        atomicAdd(&acc[a.y & BMASK], xa1);
        atomicAdd(&acc[a.z & BMASK], xa2);
        atomicAdd(&acc[a.w & BMASK], xa3);
        atomicAdd(&acc[bq.x & BMASK], xb0);
        atomicAdd(&acc[bq.y & BMASK], xb1);
        atomicAdd(&acc[bq.z & BMASK], xb2);
        atomicAdd(&acc[bq.w & BMASK], xb3);
        if (FIRST) {
            atomicAdd(&c[a.x & BMASK], 1u);
            atomicAdd(&c[a.y & BMASK], 1u);
            atomicAdd(&c[a.z & BMASK], 1u);
            atomicAdd(&c[a.w & BMASK], 1u);
            atomicAdd(&c[bq.x & BMASK], 1u);
            atomicAdd(&c[bq.y & BMASK], 1u);
            atomicAdd(&c[bq.z & BMASK], 1u);
            atomicAdd(&c[bq.w & BMASK], 1u);
        }
    }
    for (; i < i1; i += TPB_E) {                        // 4-wide remainder
        uint32x4 p = __builtin_nontemporal_load(&p4[i]);
        float x0 = x[p.x >> BSH];
        float x1 = x[p.y >> BSH];
        float x2 = x[p.z >> BSH];
        float x3 = x[p.w >> BSH];
        atomicAdd(&acc[p.x & BMASK], x0);
        atomicAdd(&acc[p.y & BMASK], x1);
        atomicAdd(&acc[p.z & BMASK], x2);
        atomicAdd(&acc[p.w & BMASK], x3);
        if (FIRST) {
            atomicAdd(&c[p.x & BMASK], 1u);
            atomicAdd(&c[p.y & BMASK], 1u);
            atomicAdd(&c[p.z & BMASK], 1u);
            atomicAdd(&c[p.w & BMASK], 1u);
        }
    }
    for (int e = a0 + ((end - a0) & ~3) + tid; e < end; e += TPB_E) {  // tail
        unsigned p = packed[e];
        atomicAdd(&acc[p & BMASK], x[p >> BSH]);
        if (FIRST) atomicAdd(&c[p & BMASK], 1u);
    }
    __syncthreads();
    int nbase = b << BSH;
    for (int idx = tid; idx < BSZ; idx += TPB_E) {
        int node = nbase + idx;
        if (node < N) {
            float rc;
            if (FIRST) {
                unsigned cv = c[idx];
                rc = 1.0f / (float)(cv > 0u ? cv : 1u);
                rcnt[node] = rc;
            } else {
                rc = rcnt[node];
            }
            outslice[node] = acc[idx] * rc;
        }
    }
}

// ---------------- fallback (proven atomic path) ----------------

#define TPB 256
#define MAX_BLOCKS 2048

__global__ void round_first(const float* __restrict__ x, const int* __restrict__ src,
                            const int* __restrict__ dst, float* __restrict__ agg,
                            float* __restrict__ cnt, int nE) {
    int i = blockIdx.x * blockDim.x + threadIdx.x;
    int stride = gridDim.x * blockDim.x;
    for (; i < nE; i += stride) {
        atomicAdd(&agg[dst[i]], x[src[i]]);
        atomicAdd(&cnt[dst[i]], 1.0f);
    }
}

__global__ void round_next(const float* __restrict__ x, const int* __restrict__ src,
                           const int* __restrict__ dst, float* __restrict__ agg, int nE) {
    int i = blockIdx.x * blockDim.x + threadIdx.x;
    int stride = gridDim.x * blockDim.x;
    for (; i < nE; i += stride) atomicAdd(&agg[dst[i]], x[src[i]]);
}

__global__ void normalize_k(float* __restrict__ out, const float* __restrict__ cnt, int n) {
    int i = blockIdx.x * blockDim.x + threadIdx.x;
    int stride = gridDim.x * blockDim.x;
    for (; i < n; i += stride) out[i] /= fmaxf(cnt[i], 1.0f);
}

// ---------------- launch ----------------

extern "C" void kernel_launch(void* const* d_in, const int* in_sizes, int n_in,
                              void* d_out, int out_size, void* d_ws, size_t ws_size,
                              hipStream_t stream) {
    const float* topic = (const float*)d_in[0];
    const int* ei  = (const int*)d_in[1];
    const int* rei = (const int*)d_in[2];
    const int N = in_sizes[0];
    const int E = in_sizes[1] / 2;

    float* out = (float*)d_out;   // 8 slices of N floats

    const int NB = (N + BSZ - 1) >> BSH;
    const int chunk = ((E + NPART * 16 - 1) / (NPART * 16)) * 16;

    // workspace layout (256B-aligned slabs)
    size_t off = 0;
    auto alloc = [&](size_t bytes) { size_t o = off; off += (bytes + 255) & ~(size_t)255; return o; };
    size_t o_packed = alloc((size_t)E * 4);
    size_t o_cnt    = alloc((size_t)N * 4);
    size_t o_blkcnt = alloc((size_t)NPART * NB * 4);
    size_t o_start  = alloc((size_t)NPART * NB * 4);
    size_t o_totals = alloc((size_t)NBMAX * 4);
    size_t o_base   = alloc((size_t)(NBMAX + 1) * 4);
    bool fast = (off <= ws_size) && (NB >= 2) && (NB <= NBMAX) &&
                (N <= (1 << 20)) && (E % 16 == 0);

    if (fast) {
        char* ws = (char*)d_ws;
        unsigned* packed = (unsigned*)(ws + o_packed);
        float*    rcnt   = (float*)   (ws + o_cnt);
        unsigned* blkcnt = (unsigned*)(ws + o_blkcnt);
        unsigned* start  = (unsigned*)(ws + o_start);
        unsigned* totals = (unsigned*)(ws + o_totals);
        unsigned* base   = (unsigned*)(ws + o_base);

        for (int dir = 0; dir < 2; ++dir) {
            const int* src = (dir == 0) ? ei : rei;
            const int* dst = src + E;
            float* oslab = out + (size_t)dir * 4 * N;

            p1_count<<<NPART, TPB_P, 0, stream>>>(dst, blkcnt, E, chunk, NB);
            s1_totals<<<NB, TPB_P, 0, stream>>>(blkcnt, totals, NB, NPART);
            s2_scan<<<1, TPB_P, 0, stream>>>(totals, base, NB);
            s3_start<<<NB, TPB_P, 0, stream>>>(blkcnt, base, start, NB, NPART);
            p2_scatter<<<NPART, TPB_P, 0, stream>>>(src, dst, start, packed, E, chunk, NB);

            e_pass<true><<<NB, TPB_E, 0, stream>>>(topic, packed, base, rcnt, oslab, N);
            for (int r = 1; r < 4; ++r) {
                e_pass<false><<<NB, TPB_E, 0, stream>>>(oslab + (size_t)(r - 1) * N, packed,
                                                        base, rcnt, oslab + (size_t)r * N, N);
            }
        }
        return;
    }

    // -------- fallback: global-atomic version --------
    const int* src = ei;
    const int* dst = ei + E;
    const int* rsrc = rei;
    const int* rdst = rei + E;

    float* cnt_f = (float*)d_ws;
    float* cnt_r = cnt_f + N;

    (void)hipMemsetAsync(d_out, 0, (size_t)out_size * sizeof(float), stream);
    (void)hipMemsetAsync(d_ws, 0, (size_t)2 * N * sizeof(float), stream);

    int eb = (E + TPB - 1) / TPB; if (eb > MAX_BLOCKS) eb = MAX_BLOCKS;
    int nb = (N + TPB - 1) / TPB; if (nb > MAX_BLOCKS) nb = MAX_BLOCKS;

    round_first<<<eb, TPB, 0, stream>>>(topic, src, dst, out, cnt_f, E);
    normalize_k<<<nb, TPB, 0, stream>>>(out, cnt_f, N);
    for (int r = 1; r < 4; ++r) {
        round_next<<<eb, TPB, 0, stream>>>(out + (size_t)(r - 1) * N, src, dst,
                                           out + (size_t)r * N, E);
        normalize_k<<<nb, TPB, 0, stream>>>(out + (size_t)r * N, cnt_f, N);
    }
    round_first<<<eb, TPB, 0, stream>>>(topic, rsrc, rdst, out + (size_t)4 * N, cnt_r, E);
    normalize_k<<<nb, TPB, 0, stream>>>(out + (size_t)4 * N, cnt_r, N);
    for (int r = 5; r < 8; ++r) {
        round_next<<<eb, TPB, 0, stream>>>(out + (size_t)(r - 1) * N, rsrc, rdst,
                                           out + (size_t)r * N, E);
        normalize_k<<<nb, TPB, 0, stream>>>(out + (size_t)r * N, cnt_r, N);
    }
}